// Round 8
// baseline (1065.707 us; speedup 1.0000x reference)
//
#include <hip/hip_runtime.h>

#define HW 3136
#define DHW 50176
#define NEL 25690112   // 8*64*16*56*56
#define CNT 401408.0f  // 8*16*56*56

typedef __attribute__((ext_vector_type(8))) short          short8;
typedef __attribute__((ext_vector_type(8))) unsigned short ushort8;
typedef __attribute__((ext_vector_type(4))) float          f32x4;

__device__ __forceinline__ unsigned f2bf(float f) {
    union { float f; unsigned u; } v; v.f = f;
    return (v.u + 0x7FFFu + ((v.u >> 16) & 1u)) >> 16;   // RNE
}
__device__ __forceinline__ float bf2f(unsigned u) {
    union { unsigned u; float f; } v; v.u = u << 16;
    return v.f;
}
// HW packed f32->bf16 RNE: 1 instr replaces ~10 VALU ops of 2x manual f2bf.
__device__ __forceinline__ unsigned cvt_pk_bf16(float lo, float hi) {
    unsigned r;
    asm("v_cvt_pk_bf16_f32 %0, %1, %2" : "=v"(r) : "v"(lo), "v"(hi));
    return r;
}

// XCD-aware swizzle for the 56x16x8 grids: XCD k (= bid % 8 round-robin)
// executes the contiguous logical range = ALL (h,d) of batch n=k, so each
// XCD's 4 MB L2 serves one n's xt/out1 slice (proven: FETCH 97->37 MB).
__device__ __forceinline__ void xcd_decode(int& h, int& d, int& n) {
    const int bid = blockIdx.x + 56 * (blockIdx.y + 16 * blockIdx.z);
    const int swz = (bid & 7) * 896 + (bid >> 3);
    h = swz % 56;
    const int dn = swz / 56;   // dn = d + 16*n, < 128
    d = dn & 15;
    n = dn >> 4;
}

// ---------------------------------------------------------------------------
// x (fp32 NCDHW) -> xt (bf16, D-innermost channels-last: [n][h*w][d][ci])
// ---------------------------------------------------------------------------
__global__ __launch_bounds__(256) void k_transpose(
    const float* __restrict__ x, unsigned short* __restrict__ xt)
{
    __shared__ unsigned lds[4][64 * 36];
    const int d = blockIdx.x, n = blockIdx.y, z = blockIdx.z;
    const int wave = threadIdx.x >> 6, lane = threadIdx.x & 63;
    const float* xb = x + (size_t)n * 64 * DHW + d * HW;
    unsigned short* xtb = xt + (size_t)n * DHW * 64;   // [hw][d][ci] inside
    unsigned* L = lds[wave];

    for (int c = z * 7 + wave; c < z * 7 + 7 && c < 49; c += 4) {
        const int P = c * 64;
#pragma unroll 4
        for (int cp = 0; cp < 32; ++cp) {
            const float a = xb[(size_t)(2 * cp) * DHW + P + lane];
            const float b = xb[(size_t)(2 * cp + 1) * DHW + P + lane];
            L[lane * 36 + cp] = cvt_pk_bf16(a, b);
        }
#pragma unroll
        for (int k = 0; k < 8; ++k) {
            const int r = (lane >> 3) + 8 * k;          // pixel within 64-chunk
            const uint4 v = *(const uint4*)&L[r * 36 + 4 * (lane & 7)];
            *(uint4*)((char*)xtb + ((size_t)(P + r) * 16 + d) * 128 + (lane & 7) * 16) = v;
        }
    }
}

// ---------------------------------------------------------------------------
// Weight prep -- LANE-MAJOR PACKED fragment layout so each per-tap B load is
// one fully-coalesced 1 KB wave read:
//   BtO[tap][ks][lane]{short8}           : 27*2*512 shorts
//   Bt1/Bt2[tap][rg][ks][lane]{short8}   : 27*4*2*512 shorts
// lane l of the load maps to row rg*16+(l&15), ci = ks*32+(l>>4)*8+e.
// ---------------------------------------------------------------------------
__global__ __launch_bounds__(256) void k_wprep(
    const float* __restrict__ w_off, const float* __restrict__ w1,
    const float* __restrict__ w2, unsigned short* __restrict__ BtO,
    unsigned short* __restrict__ Bt1, unsigned short* __restrict__ Bt2)
{
    const int i = blockIdx.x * 256 + threadIdx.x;
    if (i < 27648) {
        const int tap = i / 1024, r = i - tap * 1024;
        const int ks = r >> 9, r3 = r & 511, lane = r3 >> 3, e = r3 & 7;
        const int row = lane & 15;
        const int ci  = ks * 32 + (lane >> 4) * 8 + e;
        BtO[i] = (row < 8) ? (unsigned short)f2bf(w_off[(row * 64 + ci) * 27 + tap]) : 0;
    }
    if (i < 110592) {
        const int tap = i / 4096, r = i - tap * 4096;
        const int rg = r >> 10, r2 = r & 1023;
        const int ks = r2 >> 9, r3 = r2 & 511, lane = r3 >> 3, e = r3 & 7;
        const int co = rg * 16 + (lane & 15);
        const int ci = ks * 32 + (lane >> 4) * 8 + e;
        Bt1[i] = (unsigned short)f2bf(w1[(co * 64 + ci) * 27 + tap]);
        Bt2[i] = (unsigned short)f2bf(w2[(co * 64 + ci) * 27 + tap]);
    }
}

// ---------------------------------------------------------------------------
// Standard 3x3x3 conv via MFMA, LDS-staged. Block = (h, d, n), 512 thr.
// A-tile: 9 rows (3 dq x 3 hq) x 58 px x 64 ci bf16, row stride 72 shorts.
// Staging is ROW-STATIC: 9 fully-unrolled (kd,kh) rows, px = tid>>3 fixed ->
// scalar bounds, no divides, 9 early-issued global loads.
// NCO==8 : 8 waves, ks-SPLIT (waves 0-3: ci 0-31, waves 4-7: ci 32-63),
//          partial sums combined via two E buffers.
// NCO==64: 8 waves x (2 mf x 1 nf); epilogue FUSES per-channel stats
//          (sum/sumsq of the biased fp32 output) via shfl + global atomics.
// ---------------------------------------------------------------------------
template<int NCO, bool BN, bool DIN>
__global__ __launch_bounds__(512) void k_conv(
    const unsigned short* __restrict__ src, const unsigned short* __restrict__ Bt,
    const float* __restrict__ bias, const float* __restrict__ scv,
    const float* __restrict__ shv, float* __restrict__ dst,
    float* __restrict__ osum, float* __restrict__ osq)
{
    __shared__ unsigned short A[538 * 72];   // 9*58=522 slots + 16 overrun pad
    int h, d, n;
    xcd_decode(h, d, n);
    const int tid = threadIdx.x;
    const int wave = tid >> 6, lane = tid & 63, lm = lane & 15, quad = lane >> 4;
    const int k8 = tid & 7;                  // fixed ci-chunk per thread

    float scr[8], shr[8];
    if constexpr (BN) {
#pragma unroll
        for (int e = 0; e < 8; ++e) { scr[e] = scv[k8 * 8 + e]; shr[e] = shv[k8 * 8 + e]; }
    }

    const unsigned short* snb = DIN ? (src + (size_t)n * DHW * 64)
                                    : (src + (size_t)(n * 16) * HW * 64);

    // ---- row-static staging: 9 rows x 464 tasks (58 px x 8 chunks) ----
    const int spx = tid >> 3;                // 0..63 (>=58 masked)
    const int wq  = spx - 1;
    const bool pxok = (tid < 464) & ((unsigned)wq < 56u);
#pragma unroll
    for (int row = 0; row < 9; ++row) {
        const int kd = row / 3, kh = row - (row / 3) * 3;
        const int dq = d + kd - 1, hq = h + kh - 1;
        uint4 pk = {0u, 0u, 0u, 0u};
        if (pxok & ((unsigned)dq < 16u) & ((unsigned)hq < 56u)) {
            const size_t off = DIN ? (((size_t)(hq * 56 + wq) * 16 + dq) * 64)
                                   : (((size_t)dq * HW + hq * 56 + wq) * 64);
            const ushort8 val = *(const ushort8*)(snb + off + k8 * 8);
            if constexpr (BN) {
                float f[8];
#pragma unroll
                for (int e = 0; e < 8; ++e)
                    f[e] = fmaxf(fmaf(bf2f(val[e]), scr[e], shr[e]), 0.f);
                pk.x = cvt_pk_bf16(f[0], f[1]);
                pk.y = cvt_pk_bf16(f[2], f[3]);
                pk.z = cvt_pk_bf16(f[4], f[5]);
                pk.w = cvt_pk_bf16(f[6], f[7]);
            } else {
                pk = *(const uint4*)&val;
            }
        }
        if (tid < 464) *(uint4*)&A[(size_t)(row * 58 + spx) * 72 + k8 * 8] = pk;
    }
    __syncthreads();

    if constexpr (NCO == 8) {
        // ---- ks-split: wave>>2 picks the ci half; wave&3 picks the m-frag ----
        const int ksw = wave >> 2, mf = wave & 3;
        f32x4 acc = (f32x4){0.f, 0.f, 0.f, 0.f};
        const unsigned short* Btb = Bt + ksw * 512;
        unsigned boff = (unsigned)lane * 8;
        short8 bc = *(const short8*)(Btb + boff);
        boff += 1024u;
        unsigned arow = (unsigned)(mf * 16 + lm) * 72 + quad * 8 + ksw * 32;
#pragma unroll 1
        for (int r9 = 0; r9 < 9; ++r9) {
#pragma unroll
            for (int kw = 0; kw < 3; ++kw) {
                const bool more = (kw < 2) | (r9 < 8);
                short8 bn;
                if (more) bn = *(const short8*)(Btb + boff);
                const short8 a = *(const short8*)&A[arow + kw * 72];
                acc = __builtin_amdgcn_mfma_f32_16x16x32_bf16(a, bc, acc, 0, 0, 0);
                if (more) { bc = bn; boff += 1024u; }
            }
            arow += 58 * 72;
        }
        __syncthreads();
        float* E = (float*)A;                // E[2][56*17]
#pragma unroll
        for (int r = 0; r < 4; ++r) {
            const int mm = mf * 16 + quad * 4 + r;
            if (mm < 56) E[ksw * 952 + mm * 17 + lm] = acc[r];
        }
        __syncthreads();
        if (lane < 56) {                     // co = wave, w0 = lane
            const float v = E[lane * 17 + wave] + E[952 + lane * 17 + wave] + bias[wave];
            dst[((size_t)(n * 8 + wave) * 16 + d) * HW + h * 56 + lane] = v;
        }
    } else {
        const int mf0 = (wave & 1) * 2, nf0 = wave >> 1;
        f32x4 acc[2];
        acc[0] = (f32x4){0.f, 0.f, 0.f, 0.f};
        acc[1] = (f32x4){0.f, 0.f, 0.f, 0.f};

        const unsigned short* Btb = Bt + (unsigned)nf0 * 1024;
        unsigned boff = (unsigned)lane * 8;
        short8 bc0 = *(const short8*)(Btb + boff);
        short8 bc1 = *(const short8*)(Btb + boff + 512);
        boff += 4096u;
        unsigned arow = (unsigned)(mf0 * 16 + lm) * 72 + quad * 8;

#pragma unroll 1
        for (int r9 = 0; r9 < 9; ++r9) {
#pragma unroll
            for (int kw = 0; kw < 3; ++kw) {
                const bool more = (kw < 2) | (r9 < 8);
                short8 bn0, bn1;
                if (more) {
                    bn0 = *(const short8*)(Btb + boff);
                    bn1 = *(const short8*)(Btb + boff + 512);
                }
                const unsigned ab = arow + kw * 72;
                const short8 a00 = *(const short8*)&A[ab];
                const short8 a01 = *(const short8*)&A[ab + 1152];
                const short8 a10 = *(const short8*)&A[ab + 32];
                const short8 a11 = *(const short8*)&A[ab + 1152 + 32];
                acc[0] = __builtin_amdgcn_mfma_f32_16x16x32_bf16(a00, bc0, acc[0], 0, 0, 0);
                acc[1] = __builtin_amdgcn_mfma_f32_16x16x32_bf16(a01, bc0, acc[1], 0, 0, 0);
                acc[0] = __builtin_amdgcn_mfma_f32_16x16x32_bf16(a10, bc1, acc[0], 0, 0, 0);
                acc[1] = __builtin_amdgcn_mfma_f32_16x16x32_bf16(a11, bc1, acc[1], 0, 0, 0);
                if (more) { bc0 = bn0; bc1 = bn1; boff += 4096u; }
            }
            arow += 58 * 72;
        }

        // ---- epilogue: LDS transpose -> fp32 NCDHW + bias, FUSED stats ----
        __syncthreads();
        float* E = (float*)A;                // E[56][65]
#pragma unroll
        for (int mf = 0; mf < 2; ++mf)
#pragma unroll
            for (int r = 0; r < 4; ++r) {
                const int mm = (mf0 + mf) * 16 + quad * 4 + r;
                if (mm < 56) E[mm * 65 + nf0 * 16 + lm] = acc[mf][r];
            }
        __syncthreads();
        const int co = tid >> 3, w8 = tid & 7;     // 8 lanes per channel
        const float bco = bias[co];
        float* drow = &dst[((size_t)(n * 64 + co) * 16 + d) * HW + h * 56];
        float s = 0.f, q = 0.f;
#pragma unroll
        for (int i = 0; i < 7; ++i) {
            const int w0 = w8 + 8 * i;
            const float v = E[w0 * 65 + co] + bco;
            drow[w0] = v;
            s += v; q = fmaf(v, v, q);
        }
        s += __shfl_down(s, 1); q += __shfl_down(q, 1);
        s += __shfl_down(s, 2); q += __shfl_down(q, 2);
        s += __shfl_down(s, 4); q += __shfl_down(q, 4);
        if ((lane & 7) == 0) {
            atomicAdd(&osum[co], s);
            atomicAdd(&osq[co],  q);
        }
    }
}

// ---------------------------------------------------------------------------
// Temporal deformable conv. 512 thr, 8 waves x (2 mf x 1 nf).
// Staging BUILDS the interpolated field (g-minor dense gathers, masks folded
// into scalar lerp coefficients). Epilogue FUSES the per-channel stats of
// the bf16 output tile (replaces k_stats_bf16). Output: bf16 ch-last.
// ---------------------------------------------------------------------------
__global__ __launch_bounds__(512) void k_deform(
    const unsigned short* __restrict__ xt, const float* __restrict__ offo,
    const unsigned short* __restrict__ Bt, unsigned short* __restrict__ out1,
    float* __restrict__ osum, float* __restrict__ osq)
{
    __shared__ unsigned short A[538 * 72];
    int h, d, n;
    xcd_decode(h, d, n);
    const int tid = threadIdx.x;
    const int wave = tid >> 6, lane = tid & 63, lm = lane & 15, quad = lane >> 4;

    // ---- prefetch the 3 offset values this thread needs (g-minor decode) ----
    float pv[3];
#pragma unroll
    for (int it = 0; it < 3; ++it) {
        const int c = tid + it * 512;
        float p = 0.f;
        if (c < 1392) {
            const int g = c & 7, pix = c >> 3;           // pix < 174
            const int hq3 = pix / 58, px = pix - hq3 * 58;
            const int habs = h + hq3 - 1, wq = px - 1;
            if (((unsigned)habs < 56u) & ((unsigned)wq < 56u))
                p = offo[((size_t)(n * 8 + g) * 16 + d) * HW + habs * 56 + wq] + (float)d;
        }
        pv[it] = p;
    }

    // ---- gather + lerp staging: 1392 tasks (174 px x 8 g), g-minor ----
#pragma unroll
    for (int it = 0; it < 3; ++it) {
        const int c = tid + it * 512;
        if (c >= 1392) break;
        const int g = c & 7, pix = c >> 3;
        const int hq3 = pix / 58, px = pix - hq3 * 58;
        const int habs = h + hq3 - 1, wq = px - 1;
        uint4 p0 = {0u,0u,0u,0u}, p1 = {0u,0u,0u,0u}, p2 = {0u,0u,0u,0u};
        if (((unsigned)habs < 56u) & ((unsigned)wq < 56u)) {
            const float p = pv[it];
            const float fl = floorf(p);
            const float fr = p - fl;
            const int i0 = (int)fl;
            const unsigned short* cb = xt + ((size_t)n * HW + habs * 56 + wq) * (16 * 64) + g * 8;
            float sv[4][8], m[4];
#pragma unroll
            for (int j = 0; j < 4; ++j) {
                const int dj = i0 - 1 + j;
                const bool ok = (unsigned)dj < 16u;
                m[j] = ok ? 1.f : 0.f;
                const ushort8 v = *(const ushort8*)(cb + (size_t)(ok ? dj : 0) * 64);
#pragma unroll
                for (int e = 0; e < 8; ++e) sv[j][e] = bf2f(v[e]);   // finite data; mask in coeffs
            }
            const float fi = 1.f - fr;
            const float w0a = fi * m[0], w0b = fr * m[1];
            const float w1a = fi * m[1], w1b = fr * m[2];
            const float w2a = fi * m[2], w2b = fr * m[3];
            float a0[8], a1[8], a2[8];
#pragma unroll
            for (int e = 0; e < 8; ++e) {
                a0[e] = fmaf(sv[1][e], w0b, sv[0][e] * w0a);
                a1[e] = fmaf(sv[2][e], w1b, sv[1][e] * w1a);
                a2[e] = fmaf(sv[3][e], w2b, sv[2][e] * w2a);
            }
            p0.x = cvt_pk_bf16(a0[0], a0[1]); p0.y = cvt_pk_bf16(a0[2], a0[3]);
            p0.z = cvt_pk_bf16(a0[4], a0[5]); p0.w = cvt_pk_bf16(a0[6], a0[7]);
            p1.x = cvt_pk_bf16(a1[0], a1[1]); p1.y = cvt_pk_bf16(a1[2], a1[3]);
            p1.z = cvt_pk_bf16(a1[4], a1[5]); p1.w = cvt_pk_bf16(a1[6], a1[7]);
            p2.x = cvt_pk_bf16(a2[0], a2[1]); p2.y = cvt_pk_bf16(a2[2], a2[3]);
            p2.z = cvt_pk_bf16(a2[4], a2[5]); p2.w = cvt_pk_bf16(a2[6], a2[7]);
        }
        const int sl = hq3 * 58 + px;
        *(uint4*)&A[(size_t)(sl          ) * 72 + g * 8] = p0;   // kd=0 rows 0..2
        *(uint4*)&A[(size_t)(sl + 3 * 58 ) * 72 + g * 8] = p1;   // kd=1 rows 3..5
        *(uint4*)&A[(size_t)(sl + 6 * 58 ) * 72 + g * 8] = p2;   // kd=2 rows 6..8
    }
    __syncthreads();

    const int mf0 = (wave & 1) * 2, nf0 = wave >> 1;     // 2 mf x 1 nf per wave
    f32x4 acc[2];
    acc[0] = (f32x4){0.f, 0.f, 0.f, 0.f};
    acc[1] = (f32x4){0.f, 0.f, 0.f, 0.f};

    const unsigned short* Btb = Bt + (unsigned)nf0 * 1024;
    unsigned boff = (unsigned)lane * 8;
    short8 bc0 = *(const short8*)(Btb + boff);
    short8 bc1 = *(const short8*)(Btb + boff + 512);
    boff += 4096u;
    unsigned arow = (unsigned)(mf0 * 16 + lm) * 72 + quad * 8;

#pragma unroll 1
    for (int r9 = 0; r9 < 9; ++r9) {
#pragma unroll
        for (int kw = 0; kw < 3; ++kw) {
            const bool more = (kw < 2) | (r9 < 8);
            short8 bn0, bn1;
            if (more) {
                bn0 = *(const short8*)(Btb + boff);
                bn1 = *(const short8*)(Btb + boff + 512);
            }
            const unsigned ab = arow + kw * 72;
            const short8 a00 = *(const short8*)&A[ab];
            const short8 a01 = *(const short8*)&A[ab + 1152];
            const short8 a10 = *(const short8*)&A[ab + 32];
            const short8 a11 = *(const short8*)&A[ab + 1152 + 32];
            acc[0] = __builtin_amdgcn_mfma_f32_16x16x32_bf16(a00, bc0, acc[0], 0, 0, 0);
            acc[1] = __builtin_amdgcn_mfma_f32_16x16x32_bf16(a01, bc0, acc[1], 0, 0, 0);
            acc[0] = __builtin_amdgcn_mfma_f32_16x16x32_bf16(a10, bc1, acc[0], 0, 0, 0);
            acc[1] = __builtin_amdgcn_mfma_f32_16x16x32_bf16(a11, bc1, acc[1], 0, 0, 0);
            if (more) { bc0 = bn0; bc1 = bn1; boff += 4096u; }
        }
        arow += 58 * 72;
    }

    // ---- epilogue: bf16 tile -> LDS -> coalesced stores + FUSED stats ----
    __syncthreads();
#pragma unroll
    for (int mf = 0; mf < 2; ++mf)
#pragma unroll
        for (int r = 0; r < 4; ++r) {
            const int mm = (mf0 + mf) * 16 + quad * 4 + r;
            if (mm < 56)
                A[mm * 72 + nf0 * 16 + lm] = (unsigned short)f2bf(acc[mf][r]);
        }
    __syncthreads();
    const size_t pixb = ((size_t)(n * 16) + d) * HW + h * 56;
    if (tid < 448) {
        const int px = tid >> 3, kk = tid & 7;
        *(uint4*)(out1 + (pixb + px) * 64 + kk * 8) = *(const uint4*)&A[px * 72 + kk * 8];
    }
    // per-channel stats of the bf16 tile (replaces k_stats_bf16)
    const int co = tid >> 3, w8 = tid & 7;
    float s = 0.f, q = 0.f;
#pragma unroll
    for (int i = 0; i < 7; ++i) {
        const int w0 = w8 + 8 * i;
        const float v = bf2f(A[w0 * 72 + co]);
        s += v; q = fmaf(v, v, q);
    }
    s += __shfl_down(s, 1); q += __shfl_down(q, 1);
    s += __shfl_down(s, 2); q += __shfl_down(q, 2);
    s += __shfl_down(s, 4); q += __shfl_down(q, 4);
    if ((lane & 7) == 0) {
        atomicAdd(&osum[co], s);
        atomicAdd(&osq[co],  q);
    }
}

// ---------------- finalize BN: scale/shift ---------------------------------
__global__ void k_finalize(const float* __restrict__ sums, const float* __restrict__ sqs,
                           const float* __restrict__ gamma, const float* __restrict__ beta,
                           float* __restrict__ scale, float* __restrict__ shift)
{
    const int c = threadIdx.x; // 64 threads
    const float mean = sums[c] / CNT;
    const float var  = sqs[c] / CNT - mean * mean;
    const float sc   = gamma[c] * rsqrtf(var + 1e-5f);
    scale[c] = sc;
    shift[c] = fmaf(-mean, sc, beta[c]);
}

// -------- BN2 + residual + ReLU: dst = relu(bn(raw) + x)  (float4) ---------
__global__ __launch_bounds__(256) void k_residual(
    float4* __restrict__ dst, const float4* __restrict__ raw,
    const float4* __restrict__ x,
    const float* __restrict__ scale, const float* __restrict__ shift)
{
    const int i = blockIdx.x * 256 + threadIdx.x;   // < 6422528
    const int c = (i / 12544) & 63;                  // wave-uniform
    const float sc = scale[c], sh = shift[c];
    float4 v = raw[i];
    const float4 xv = x[i];
    v.x = fmaxf(fmaf(v.x, sc, sh) + xv.x, 0.f);
    v.y = fmaxf(fmaf(v.y, sc, sh) + xv.y, 0.f);
    v.z = fmaxf(fmaf(v.z, sc, sh) + xv.z, 0.f);
    v.w = fmaxf(fmaf(v.w, sc, sh) + xv.w, 0.f);
    dst[i] = v;
}

extern "C" void kernel_launch(void* const* d_in, const int* in_sizes, int n_in,
                              void* d_out, int out_size, void* d_ws, size_t ws_size,
                              hipStream_t stream) {
    const float* x     = (const float*)d_in[0];
    const float* w_off = (const float*)d_in[1];
    const float* b_off = (const float*)d_in[2];
    const float* w1    = (const float*)d_in[3];
    const float* w2    = (const float*)d_in[4];
    const float* b2    = (const float*)d_in[5];
    const float* g1    = (const float*)d_in[6];
    const float* be1   = (const float*)d_in[7];
    const float* g2    = (const float*)d_in[8];
    const float* be2   = (const float*)d_in[9];

    // ---- buffer plan ----
    // d_out: [0, 2*NEL) bytes      : out1 (deform result, bf16 ch-last) -- dead after k_conv<64>
    //        byte 52,000,000       : weight blocks (bf16) -- dead after k_conv<64>
    //        [4*NEL, ...) bytes    : off output (fp32, final)
    //        [0, 4*NEL) bytes      : final out (fp32), written LAST by k_residual
    // d_ws:  [0, 2*NEL) bytes      : xt (bf16 D-innermost x) -- dead after k_deform
    //        [0, 4*NEL) bytes      : raw (conv2 output fp32 NCDHW) overwrites xt
    //        [4*NEL, +2KiB)        : st stats block
    float* out     = (float*)d_out;
    float* off_out = out + NEL;
    unsigned short* out1 = (unsigned short*)d_out;
    unsigned short* wb   = (unsigned short*)(out + 13000000);  // byte 52,000,000
    unsigned short* BtO  = wb;
    unsigned short* Bt1  = BtO + 27648;
    unsigned short* Bt2  = Bt1 + 110592;

    unsigned short* xt  = (unsigned short*)d_ws;
    float*          raw = (float*)d_ws;
    float*          st  = (float*)d_ws + NEL;   // bytes [4*NEL, 4*NEL+2048)
    // st: 0 sum1 | 64 sq1 | 128 sc1 | 192 sh1 | 256 sum2 | 320 sq2 | 384 sc2 | 448 sh2

    hipMemsetAsync(st, 0, 512 * sizeof(float), stream);

    k_transpose<<<dim3(16, 8, 7), 256, 0, stream>>>(x, xt);
    k_wprep<<<432, 256, 0, stream>>>(w_off, w1, w2, BtO, Bt1, Bt2);

    const dim3 cgrid(56, 16, 8);   // h, d, n (decoded via xcd_decode inside)
    k_conv<8, false, true><<<cgrid, 512, 0, stream>>>(xt, BtO, b_off, nullptr, nullptr, off_out, nullptr, nullptr);
    k_deform<<<cgrid, 512, 0, stream>>>(xt, off_out, Bt1, out1, st + 0, st + 64);

    k_finalize<<<1, 64, 0, stream>>>(st + 0, st + 64, g1, be1, st + 128, st + 192);

    k_conv<64, true, false><<<cgrid, 512, 0, stream>>>(out1, Bt2, b2, st + 128, st + 192, raw, st + 256, st + 320);

    k_finalize<<<1, 64, 0, stream>>>(st + 256, st + 320, g2, be2, st + 384, st + 448);
    k_residual<<<25088, 256, 0, stream>>>((float4*)out, (const float4*)raw, (const float4*)x, st + 384, st + 448);
}

// Round 10
// 656.757 us; speedup vs baseline: 1.6227x; 1.6227x over previous
//
#include <hip/hip_runtime.h>

#define HW 3136
#define DHW 50176
#define NEL 25690112   // 8*64*16*56*56
#define CNT 401408.0f  // 8*16*56*56

typedef __attribute__((ext_vector_type(8))) short          short8;
typedef __attribute__((ext_vector_type(8))) unsigned short ushort8;
typedef __attribute__((ext_vector_type(4))) float          f32x4;

__device__ __forceinline__ unsigned f2bf(float f) {
    union { float f; unsigned u; } v; v.f = f;
    return (v.u + 0x7FFFu + ((v.u >> 16) & 1u)) >> 16;   // RNE
}
__device__ __forceinline__ float bf2f(unsigned u) {
    union { unsigned u; float f; } v; v.u = u << 16;
    return v.f;
}
// HW packed f32->bf16 RNE: 1 instr replaces ~10 VALU ops of 2x manual f2bf.
__device__ __forceinline__ unsigned cvt_pk_bf16(float lo, float hi) {
    unsigned r;
    asm("v_cvt_pk_bf16_f32 %0, %1, %2" : "=v"(r) : "v"(lo), "v"(hi));
    return r;
}

// XCD-aware swizzle for the 56x16x8 grids: XCD k (= bid % 8 round-robin)
// executes the contiguous logical range = ALL (h,d) of batch n=k, so each
// XCD's 4 MB L2 serves one n's xt/out1 slice (proven: FETCH 97->37 MB).
// Also returns a 64-way stats bucket id (round-8 lesson: distribute atomic
// contention -- 7168 blocks x 128 atomics on 4 lines serialized ~200us).
__device__ __forceinline__ void xcd_decode(int& h, int& d, int& n, int& bucket) {
    const int bid = blockIdx.x + 56 * (blockIdx.y + 16 * blockIdx.z);
    bucket = bid & 63;
    const int swz = (bid & 7) * 896 + (bid >> 3);
    h = swz % 56;
    const int dn = swz / 56;   // dn = d + 16*n, < 128
    d = dn & 15;
    n = dn >> 4;
}

// ---------------------------------------------------------------------------
// x (fp32 NCDHW) -> xt (bf16, D-innermost channels-last: [n][h*w][d][ci])
// ---------------------------------------------------------------------------
__global__ __launch_bounds__(256) void k_transpose(
    const float* __restrict__ x, unsigned short* __restrict__ xt)
{
    __shared__ unsigned lds[4][64 * 36];
    const int d = blockIdx.x, n = blockIdx.y, z = blockIdx.z;
    const int wave = threadIdx.x >> 6, lane = threadIdx.x & 63;
    const float* xb = x + (size_t)n * 64 * DHW + d * HW;
    unsigned short* xtb = xt + (size_t)n * DHW * 64;   // [hw][d][ci] inside
    unsigned* L = lds[wave];

    for (int c = z * 7 + wave; c < z * 7 + 7 && c < 49; c += 4) {
        const int P = c * 64;
#pragma unroll 4
        for (int cp = 0; cp < 32; ++cp) {
            const float a = xb[(size_t)(2 * cp) * DHW + P + lane];
            const float b = xb[(size_t)(2 * cp + 1) * DHW + P + lane];
            L[lane * 36 + cp] = cvt_pk_bf16(a, b);
        }
#pragma unroll
        for (int k = 0; k < 8; ++k) {
            const int r = (lane >> 3) + 8 * k;          // pixel within 64-chunk
            const uint4 v = *(const uint4*)&L[r * 36 + 4 * (lane & 7)];
            *(uint4*)((char*)xtb + ((size_t)(P + r) * 16 + d) * 128 + (lane & 7) * 16) = v;
        }
    }
}

// ---------------------------------------------------------------------------
// Weight prep -- LANE-MAJOR PACKED fragment layout so each per-tap B load is
// one fully-coalesced 1 KB wave read:
//   BtO[tap][ks][lane]{short8}           : 27*2*512 shorts
//   Bt1/Bt2[tap][rg][ks][lane]{short8}   : 27*4*2*512 shorts
// lane l of the load maps to row rg*16+(l&15), ci = ks*32+(l>>4)*8+e.
// ---------------------------------------------------------------------------
__global__ __launch_bounds__(256) void k_wprep(
    const float* __restrict__ w_off, const float* __restrict__ w1,
    const float* __restrict__ w2, unsigned short* __restrict__ BtO,
    unsigned short* __restrict__ Bt1, unsigned short* __restrict__ Bt2)
{
    const int i = blockIdx.x * 256 + threadIdx.x;
    if (i < 27648) {
        const int tap = i / 1024, r = i - tap * 1024;
        const int ks = r >> 9, r3 = r & 511, lane = r3 >> 3, e = r3 & 7;
        const int row = lane & 15;
        const int ci  = ks * 32 + (lane >> 4) * 8 + e;
        BtO[i] = (row < 8) ? (unsigned short)f2bf(w_off[(row * 64 + ci) * 27 + tap]) : 0;
    }
    if (i < 110592) {
        const int tap = i / 4096, r = i - tap * 4096;
        const int rg = r >> 10, r2 = r & 1023;
        const int ks = r2 >> 9, r3 = r2 & 511, lane = r3 >> 3, e = r3 & 7;
        const int co = rg * 16 + (lane & 15);
        const int ci = ks * 32 + (lane >> 4) * 8 + e;
        Bt1[i] = (unsigned short)f2bf(w1[(co * 64 + ci) * 27 + tap]);
        Bt2[i] = (unsigned short)f2bf(w2[(co * 64 + ci) * 27 + tap]);
    }
}

// ---------------------------------------------------------------------------
// Standard 3x3x3 conv via MFMA, LDS-staged. Block = (h, d, n), 512 thr.
// A-tile: 9 rows (3 dq x 3 hq) x 58 px x 64 ci bf16, row stride 72 shorts.
// Staging is ROW-STATIC: 9 fully-unrolled (kd,kh) rows, px = tid>>3 fixed ->
// scalar bounds, no divides, 9 early-issued global loads.
// NCO==8 : 8 waves, ks-SPLIT (waves 0-3: ci 0-31, waves 4-7: ci 32-63),
//          partial sums combined via two E buffers.
// NCO==64: 8 waves x (2 mf x 1 nf); epilogue FUSES per-channel stats into
//          BUCKETED accumulators (osum/osq are [64 buckets][64 ch]).
// ---------------------------------------------------------------------------
template<int NCO, bool BN, bool DIN>
__global__ __launch_bounds__(512) void k_conv(
    const unsigned short* __restrict__ src, const unsigned short* __restrict__ Bt,
    const float* __restrict__ bias, const float* __restrict__ scv,
    const float* __restrict__ shv, float* __restrict__ dst,
    float* __restrict__ osum, float* __restrict__ osq)
{
    __shared__ unsigned short A[538 * 72];   // 9*58=522 slots + 16 overrun pad
    int h, d, n, bucket;
    xcd_decode(h, d, n, bucket);
    const int tid = threadIdx.x;
    const int wave = tid >> 6, lane = tid & 63, lm = lane & 15, quad = lane >> 4;
    const int k8 = tid & 7;                  // fixed ci-chunk per thread

    float scr[8], shr[8];
    if constexpr (BN) {
#pragma unroll
        for (int e = 0; e < 8; ++e) { scr[e] = scv[k8 * 8 + e]; shr[e] = shv[k8 * 8 + e]; }
    }

    const unsigned short* snb = DIN ? (src + (size_t)n * DHW * 64)
                                    : (src + (size_t)(n * 16) * HW * 64);

    // ---- row-static staging: 9 rows x 464 tasks (58 px x 8 chunks) ----
    const int spx = tid >> 3;                // 0..63 (>=58 masked)
    const int wq  = spx - 1;
    const bool pxok = (tid < 464) & ((unsigned)wq < 56u);
#pragma unroll
    for (int row = 0; row < 9; ++row) {
        const int kd = row / 3, kh = row - (row / 3) * 3;
        const int dq = d + kd - 1, hq = h + kh - 1;
        uint4 pk = {0u, 0u, 0u, 0u};
        if (pxok & ((unsigned)dq < 16u) & ((unsigned)hq < 56u)) {
            const size_t off = DIN ? (((size_t)(hq * 56 + wq) * 16 + dq) * 64)
                                   : (((size_t)dq * HW + hq * 56 + wq) * 64);
            const ushort8 val = *(const ushort8*)(snb + off + k8 * 8);
            if constexpr (BN) {
                float f[8];
#pragma unroll
                for (int e = 0; e < 8; ++e)
                    f[e] = fmaxf(fmaf(bf2f(val[e]), scr[e], shr[e]), 0.f);
                pk.x = cvt_pk_bf16(f[0], f[1]);
                pk.y = cvt_pk_bf16(f[2], f[3]);
                pk.z = cvt_pk_bf16(f[4], f[5]);
                pk.w = cvt_pk_bf16(f[6], f[7]);
            } else {
                pk = *(const uint4*)&val;
            }
        }
        if (tid < 464) *(uint4*)&A[(size_t)(row * 58 + spx) * 72 + k8 * 8] = pk;
    }
    __syncthreads();

    if constexpr (NCO == 8) {
        // ---- ks-split: wave>>2 picks the ci half; wave&3 picks the m-frag ----
        const int ksw = wave >> 2, mf = wave & 3;
        f32x4 acc = (f32x4){0.f, 0.f, 0.f, 0.f};
        const unsigned short* Btb = Bt + ksw * 512;
        unsigned boff = (unsigned)lane * 8;
        short8 bc = *(const short8*)(Btb + boff);
        boff += 1024u;
        unsigned arow = (unsigned)(mf * 16 + lm) * 72 + quad * 8 + ksw * 32;
#pragma unroll 1
        for (int r9 = 0; r9 < 9; ++r9) {
#pragma unroll
            for (int kw = 0; kw < 3; ++kw) {
                const bool more = (kw < 2) | (r9 < 8);
                short8 bn;
                if (more) bn = *(const short8*)(Btb + boff);
                const short8 a = *(const short8*)&A[arow + kw * 72];
                acc = __builtin_amdgcn_mfma_f32_16x16x32_bf16(a, bc, acc, 0, 0, 0);
                if (more) { bc = bn; boff += 1024u; }
            }
            arow += 58 * 72;
        }
        __syncthreads();
        float* E = (float*)A;                // E[2][56*17]
#pragma unroll
        for (int r = 0; r < 4; ++r) {
            const int mm = mf * 16 + quad * 4 + r;
            if (mm < 56) E[ksw * 952 + mm * 17 + lm] = acc[r];
        }
        __syncthreads();
        if (lane < 56) {                     // co = wave, w0 = lane
            const float v = E[lane * 17 + wave] + E[952 + lane * 17 + wave] + bias[wave];
            dst[((size_t)(n * 8 + wave) * 16 + d) * HW + h * 56 + lane] = v;
        }
    } else {
        const int mf0 = (wave & 1) * 2, nf0 = wave >> 1;
        f32x4 acc[2];
        acc[0] = (f32x4){0.f, 0.f, 0.f, 0.f};
        acc[1] = (f32x4){0.f, 0.f, 0.f, 0.f};

        const unsigned short* Btb = Bt + (unsigned)nf0 * 1024;
        unsigned boff = (unsigned)lane * 8;
        short8 bc0 = *(const short8*)(Btb + boff);
        short8 bc1 = *(const short8*)(Btb + boff + 512);
        boff += 4096u;
        unsigned arow = (unsigned)(mf0 * 16 + lm) * 72 + quad * 8;

#pragma unroll 1
        for (int r9 = 0; r9 < 9; ++r9) {
#pragma unroll
            for (int kw = 0; kw < 3; ++kw) {
                const bool more = (kw < 2) | (r9 < 8);
                short8 bn0, bn1;
                if (more) {
                    bn0 = *(const short8*)(Btb + boff);
                    bn1 = *(const short8*)(Btb + boff + 512);
                }
                const unsigned ab = arow + kw * 72;
                const short8 a00 = *(const short8*)&A[ab];
                const short8 a01 = *(const short8*)&A[ab + 1152];
                const short8 a10 = *(const short8*)&A[ab + 32];
                const short8 a11 = *(const short8*)&A[ab + 1152 + 32];
                acc[0] = __builtin_amdgcn_mfma_f32_16x16x32_bf16(a00, bc0, acc[0], 0, 0, 0);
                acc[1] = __builtin_amdgcn_mfma_f32_16x16x32_bf16(a01, bc0, acc[1], 0, 0, 0);
                acc[0] = __builtin_amdgcn_mfma_f32_16x16x32_bf16(a10, bc1, acc[0], 0, 0, 0);
                acc[1] = __builtin_amdgcn_mfma_f32_16x16x32_bf16(a11, bc1, acc[1], 0, 0, 0);
                if (more) { bc0 = bn0; bc1 = bn1; boff += 4096u; }
            }
            arow += 58 * 72;
        }

        // ---- epilogue: LDS transpose -> fp32 NCDHW + bias, FUSED stats ----
        __syncthreads();
        float* E = (float*)A;                // E[56][65]
#pragma unroll
        for (int mf = 0; mf < 2; ++mf)
#pragma unroll
            for (int r = 0; r < 4; ++r) {
                const int mm = (mf0 + mf) * 16 + quad * 4 + r;
                if (mm < 56) E[mm * 65 + nf0 * 16 + lm] = acc[mf][r];
            }
        __syncthreads();
        const int co = tid >> 3, w8 = tid & 7;     // 8 lanes per channel
        const float bco = bias[co];
        float* drow = &dst[((size_t)(n * 64 + co) * 16 + d) * HW + h * 56];
        float s = 0.f, q = 0.f;
#pragma unroll
        for (int i = 0; i < 7; ++i) {
            const int w0 = w8 + 8 * i;
            const float v = E[w0 * 65 + co] + bco;
            drow[w0] = v;
            s += v; q = fmaf(v, v, q);
        }
        s += __shfl_down(s, 1); q += __shfl_down(q, 1);
        s += __shfl_down(s, 2); q += __shfl_down(q, 2);
        s += __shfl_down(s, 4); q += __shfl_down(q, 4);
        if ((lane & 7) == 0) {
            atomicAdd(&osum[(bucket << 6) + co], s);
            atomicAdd(&osq [(bucket << 6) + co], q);
        }
    }
}

// ---------------------------------------------------------------------------
// Temporal deformable conv. 512 thr, 8 waves x (2 mf x 1 nf).
// Staging BUILDS the interpolated field (g-minor dense gathers, masks folded
// into scalar lerp coefficients). Epilogue FUSES per-channel stats into
// BUCKETED accumulators. Output: bf16 ch-last.
// ---------------------------------------------------------------------------
__global__ __launch_bounds__(512) void k_deform(
    const unsigned short* __restrict__ xt, const float* __restrict__ offo,
    const unsigned short* __restrict__ Bt, unsigned short* __restrict__ out1,
    float* __restrict__ osum, float* __restrict__ osq)
{
    __shared__ unsigned short A[538 * 72];
    int h, d, n, bucket;
    xcd_decode(h, d, n, bucket);
    const int tid = threadIdx.x;
    const int wave = tid >> 6, lane = tid & 63, lm = lane & 15, quad = lane >> 4;

    // ---- prefetch the 3 offset values this thread needs (g-minor decode) ----
    float pv[3];
#pragma unroll
    for (int it = 0; it < 3; ++it) {
        const int c = tid + it * 512;
        float p = 0.f;
        if (c < 1392) {
            const int g = c & 7, pix = c >> 3;           // pix < 174
            const int hq3 = pix / 58, px = pix - hq3 * 58;
            const int habs = h + hq3 - 1, wq = px - 1;
            if (((unsigned)habs < 56u) & ((unsigned)wq < 56u))
                p = offo[((size_t)(n * 8 + g) * 16 + d) * HW + habs * 56 + wq] + (float)d;
        }
        pv[it] = p;
    }

    // ---- gather + lerp staging: 1392 tasks (174 px x 8 g), g-minor ----
#pragma unroll
    for (int it = 0; it < 3; ++it) {
        const int c = tid + it * 512;
        if (c >= 1392) break;
        const int g = c & 7, pix = c >> 3;
        const int hq3 = pix / 58, px = pix - hq3 * 58;
        const int habs = h + hq3 - 1, wq = px - 1;
        uint4 p0 = {0u,0u,0u,0u}, p1 = {0u,0u,0u,0u}, p2 = {0u,0u,0u,0u};
        if (((unsigned)habs < 56u) & ((unsigned)wq < 56u)) {
            const float p = pv[it];
            const float fl = floorf(p);
            const float fr = p - fl;
            const int i0 = (int)fl;
            const unsigned short* cb = xt + ((size_t)n * HW + habs * 56 + wq) * (16 * 64) + g * 8;
            float sv[4][8], m[4];
#pragma unroll
            for (int j = 0; j < 4; ++j) {
                const int dj = i0 - 1 + j;
                const bool ok = (unsigned)dj < 16u;
                m[j] = ok ? 1.f : 0.f;
                const ushort8 v = *(const ushort8*)(cb + (size_t)(ok ? dj : 0) * 64);
#pragma unroll
                for (int e = 0; e < 8; ++e) sv[j][e] = bf2f(v[e]);   // finite data; mask in coeffs
            }
            const float fi = 1.f - fr;
            const float w0a = fi * m[0], w0b = fr * m[1];
            const float w1a = fi * m[1], w1b = fr * m[2];
            const float w2a = fi * m[2], w2b = fr * m[3];
            float a0[8], a1[8], a2[8];
#pragma unroll
            for (int e = 0; e < 8; ++e) {
                a0[e] = fmaf(sv[1][e], w0b, sv[0][e] * w0a);
                a1[e] = fmaf(sv[2][e], w1b, sv[1][e] * w1a);
                a2[e] = fmaf(sv[3][e], w2b, sv[2][e] * w2a);
            }
            p0.x = cvt_pk_bf16(a0[0], a0[1]); p0.y = cvt_pk_bf16(a0[2], a0[3]);
            p0.z = cvt_pk_bf16(a0[4], a0[5]); p0.w = cvt_pk_bf16(a0[6], a0[7]);
            p1.x = cvt_pk_bf16(a1[0], a1[1]); p1.y = cvt_pk_bf16(a1[2], a1[3]);
            p1.z = cvt_pk_bf16(a1[4], a1[5]); p1.w = cvt_pk_bf16(a1[6], a1[7]);
            p2.x = cvt_pk_bf16(a2[0], a2[1]); p2.y = cvt_pk_bf16(a2[2], a2[3]);
            p2.z = cvt_pk_bf16(a2[4], a2[5]); p2.w = cvt_pk_bf16(a2[6], a2[7]);
        }
        const int sl = hq3 * 58 + px;
        *(uint4*)&A[(size_t)(sl          ) * 72 + g * 8] = p0;   // kd=0 rows 0..2
        *(uint4*)&A[(size_t)(sl + 3 * 58 ) * 72 + g * 8] = p1;   // kd=1 rows 3..5
        *(uint4*)&A[(size_t)(sl + 6 * 58 ) * 72 + g * 8] = p2;   // kd=2 rows 6..8
    }
    __syncthreads();

    const int mf0 = (wave & 1) * 2, nf0 = wave >> 1;     // 2 mf x 1 nf per wave
    f32x4 acc[2];
    acc[0] = (f32x4){0.f, 0.f, 0.f, 0.f};
    acc[1] = (f32x4){0.f, 0.f, 0.f, 0.f};

    const unsigned short* Btb = Bt + (unsigned)nf0 * 1024;
    unsigned boff = (unsigned)lane * 8;
    short8 bc0 = *(const short8*)(Btb + boff);
    short8 bc1 = *(const short8*)(Btb + boff + 512);
    boff += 4096u;
    unsigned arow = (unsigned)(mf0 * 16 + lm) * 72 + quad * 8;

#pragma unroll 1
    for (int r9 = 0; r9 < 9; ++r9) {
#pragma unroll
        for (int kw = 0; kw < 3; ++kw) {
            const bool more = (kw < 2) | (r9 < 8);
            short8 bn0, bn1;
            if (more) {
                bn0 = *(const short8*)(Btb + boff);
                bn1 = *(const short8*)(Btb + boff + 512);
            }
            const unsigned ab = arow + kw * 72;
            const short8 a00 = *(const short8*)&A[ab];
            const short8 a01 = *(const short8*)&A[ab + 1152];
            const short8 a10 = *(const short8*)&A[ab + 32];
            const short8 a11 = *(const short8*)&A[ab + 1152 + 32];
            acc[0] = __builtin_amdgcn_mfma_f32_16x16x32_bf16(a00, bc0, acc[0], 0, 0, 0);
            acc[1] = __builtin_amdgcn_mfma_f32_16x16x32_bf16(a01, bc0, acc[1], 0, 0, 0);
            acc[0] = __builtin_amdgcn_mfma_f32_16x16x32_bf16(a10, bc1, acc[0], 0, 0, 0);
            acc[1] = __builtin_amdgcn_mfma_f32_16x16x32_bf16(a11, bc1, acc[1], 0, 0, 0);
            if (more) { bc0 = bn0; bc1 = bn1; boff += 4096u; }
        }
        arow += 58 * 72;
    }

    // ---- epilogue: bf16 tile -> LDS -> coalesced stores + FUSED stats ----
    __syncthreads();
#pragma unroll
    for (int mf = 0; mf < 2; ++mf)
#pragma unroll
        for (int r = 0; r < 4; ++r) {
            const int mm = (mf0 + mf) * 16 + quad * 4 + r;
            if (mm < 56)
                A[mm * 72 + nf0 * 16 + lm] = (unsigned short)f2bf(acc[mf][r]);
        }
    __syncthreads();
    const size_t pixb = ((size_t)(n * 16) + d) * HW + h * 56;
    if (tid < 448) {
        const int px = tid >> 3, kk = tid & 7;
        *(uint4*)(out1 + (pixb + px) * 64 + kk * 8) = *(const uint4*)&A[px * 72 + kk * 8];
    }
    // per-channel stats of the bf16 tile (bucketed; replaces k_stats_bf16)
    const int co = tid >> 3, w8 = tid & 7;
    float s = 0.f, q = 0.f;
#pragma unroll
    for (int i = 0; i < 7; ++i) {
        const int w0 = w8 + 8 * i;
        const float v = bf2f(A[w0 * 72 + co]);
        s += v; q = fmaf(v, v, q);
    }
    s += __shfl_down(s, 1); q += __shfl_down(q, 1);
    s += __shfl_down(s, 2); q += __shfl_down(q, 2);
    s += __shfl_down(s, 4); q += __shfl_down(q, 4);
    if ((lane & 7) == 0) {
        atomicAdd(&osum[(bucket << 6) + co], s);
        atomicAdd(&osq [(bucket << 6) + co], q);
    }
}

// ---------------- finalize BN from bucketed sums: scale/shift --------------
__global__ void k_finalize(const float* __restrict__ sums, const float* __restrict__ sqs,
                           const float* __restrict__ gamma, const float* __restrict__ beta,
                           float* __restrict__ scale, float* __restrict__ shift)
{
    const int c = threadIdx.x; // 64 threads
    float s = 0.f, q = 0.f;
#pragma unroll 8
    for (int b = 0; b < 64; ++b) {
        s += sums[(b << 6) + c];
        q += sqs [(b << 6) + c];
    }
    const float mean = s / CNT;
    const float var  = q / CNT - mean * mean;
    const float sc   = gamma[c] * rsqrtf(var + 1e-5f);
    scale[c] = sc;
    shift[c] = fmaf(-mean, sc, beta[c]);
}

// -------- BN2 + residual + ReLU: dst = relu(bn(raw) + x)  (float4) ---------
__global__ __launch_bounds__(256) void k_residual(
    float4* __restrict__ dst, const float4* __restrict__ raw,
    const float4* __restrict__ x,
    const float* __restrict__ scale, const float* __restrict__ shift)
{
    const int i = blockIdx.x * 256 + threadIdx.x;   // < 6422528
    const int c = (i / 12544) & 63;                  // wave-uniform
    const float sc = scale[c], sh = shift[c];
    float4 v = raw[i];
    const float4 xv = x[i];
    v.x = fmaxf(fmaf(v.x, sc, sh) + xv.x, 0.f);
    v.y = fmaxf(fmaf(v.y, sc, sh) + xv.y, 0.f);
    v.z = fmaxf(fmaf(v.z, sc, sh) + xv.z, 0.f);
    v.w = fmaxf(fmaf(v.w, sc, sh) + xv.w, 0.f);
    dst[i] = v;
}

extern "C" void kernel_launch(void* const* d_in, const int* in_sizes, int n_in,
                              void* d_out, int out_size, void* d_ws, size_t ws_size,
                              hipStream_t stream) {
    const float* x     = (const float*)d_in[0];
    const float* w_off = (const float*)d_in[1];
    const float* b_off = (const float*)d_in[2];
    const float* w1    = (const float*)d_in[3];
    const float* w2    = (const float*)d_in[4];
    const float* b2    = (const float*)d_in[5];
    const float* g1    = (const float*)d_in[6];
    const float* be1   = (const float*)d_in[7];
    const float* g2    = (const float*)d_in[8];
    const float* be2   = (const float*)d_in[9];

    // ---- buffer plan ----
    // d_out: [0, 2*NEL) bytes      : out1 (deform bf16 ch-last) -- dead after k_conv<64>
    //        byte 52,000,000       : weight blocks (bf16) -- dead after k_conv<64>
    //        byte 53,000,000       : BUCKETED stats accumulators (16384 floats)
    //                                -- dead after the k_finalize that reads them,
    //                                which COMPLETES (stream order) before
    //                                k_residual's overwrite. NOTHING read by
    //                                k_residual lives in d_out (round-9 bug fix:
    //                                sc/sh moved to d_ws -- k_residual both read
    //                                and wrote d_out[53M], intra-kernel race).
    //        [4*NEL, ...) bytes    : off output (fp32, final)
    //        [0, 4*NEL) bytes      : final out (fp32), written LAST by k_residual
    // d_ws:  [0, 2*NEL) bytes      : xt (bf16 D-innermost x) -- dead after k_deform
    //        [0, 4*NEL) bytes      : raw (conv2 output fp32 NCDHW) overwrites xt
    //        [4*NEL, +1KiB)        : sc1/sh1/sc2/sh2 (256 floats; within the
    //                                round-0..7-proven 2 KiB st footprint)
    float* out     = (float*)d_out;
    float* off_out = out + NEL;
    unsigned short* out1 = (unsigned short*)d_out;
    unsigned short* wb   = (unsigned short*)(out + 13000000);  // byte 52,000,000
    unsigned short* BtO  = wb;
    unsigned short* Bt1  = BtO + 27648;
    unsigned short* Bt2  = Bt1 + 110592;

    unsigned short* xt  = (unsigned short*)d_ws;
    float*          raw = (float*)d_ws;

    float* stb = (float*)((char*)d_out + 53000000);   // buckets ONLY
    // stb: [0,4096) dsum buckets | [4096,8192) dsq | [8192,12288) csum | [12288,16384) csq
    float* dsum = stb,        * dsq = stb + 4096;
    float* csum = stb + 8192, * csq = stb + 12288;
    float* shp = (float*)d_ws + NEL;                  // proven 2 KiB region
    float* sc1 = shp,       * sh1 = shp + 64;
    float* sc2 = shp + 128, * sh2 = shp + 192;

    hipMemsetAsync(stb, 0, 16384 * sizeof(float), stream);

    k_transpose<<<dim3(16, 8, 7), 256, 0, stream>>>(x, xt);
    k_wprep<<<432, 256, 0, stream>>>(w_off, w1, w2, BtO, Bt1, Bt2);

    const dim3 cgrid(56, 16, 8);   // h, d, n (decoded via xcd_decode inside)
    k_conv<8, false, true><<<cgrid, 512, 0, stream>>>(xt, BtO, b_off, nullptr, nullptr, off_out, nullptr, nullptr);
    k_deform<<<cgrid, 512, 0, stream>>>(xt, off_out, Bt1, out1, dsum, dsq);

    k_finalize<<<1, 64, 0, stream>>>(dsum, dsq, g1, be1, sc1, sh1);

    k_conv<64, true, false><<<cgrid, 512, 0, stream>>>(out1, Bt2, b2, sc1, sh1, raw, csum, csq);

    k_finalize<<<1, 64, 0, stream>>>(csum, csq, g2, be2, sc2, sh2);
    k_residual<<<25088, 256, 0, stream>>>((float4*)out, (const float4*)raw, (const float4*)x, sc2, sh2);
}

// Round 11
// 652.647 us; speedup vs baseline: 1.6329x; 1.0063x over previous
//
#include <hip/hip_runtime.h>

#define HW 3136
#define DHW 50176
#define NEL 25690112   // 8*64*16*56*56
#define CNT 401408.0f  // 8*16*56*56

typedef __attribute__((ext_vector_type(8)))  short          short8;
typedef __attribute__((ext_vector_type(8)))  unsigned short ushort8;
typedef __attribute__((ext_vector_type(4)))  float          f32x4;
typedef __attribute__((ext_vector_type(16))) float          f32x16;

__device__ __forceinline__ unsigned f2bf(float f) {
    union { float f; unsigned u; } v; v.f = f;
    return (v.u + 0x7FFFu + ((v.u >> 16) & 1u)) >> 16;   // RNE
}
__device__ __forceinline__ float bf2f(unsigned u) {
    union { unsigned u; float f; } v; v.u = u << 16;
    return v.f;
}
// HW packed f32->bf16 RNE: 1 instr replaces ~10 VALU ops of 2x manual f2bf.
__device__ __forceinline__ unsigned cvt_pk_bf16(float lo, float hi) {
    unsigned r;
    asm("v_cvt_pk_bf16_f32 %0, %1, %2" : "=v"(r) : "v"(lo), "v"(hi));
    return r;
}

// XCD-aware swizzle for the 56x16x8 grids: XCD k (= bid % 8 round-robin)
// executes the contiguous logical range = ALL (h,d) of batch n=k, so each
// XCD's 4 MB L2 serves one n's xt/out1 slice (proven: FETCH 97->37 MB).
// Also returns a 64-way stats bucket id (round-8 lesson: distribute atomic
// contention -- 7168 blocks x 128 atomics on 4 lines serialized ~200us).
__device__ __forceinline__ void xcd_decode(int& h, int& d, int& n, int& bucket) {
    const int bid = blockIdx.x + 56 * (blockIdx.y + 16 * blockIdx.z);
    bucket = bid & 63;
    const int swz = (bid & 7) * 896 + (bid >> 3);
    h = swz % 56;
    const int dn = swz / 56;   // dn = d + 16*n, < 128
    d = dn & 15;
    n = dn >> 4;
}

// ---------------------------------------------------------------------------
// x (fp32 NCDHW) -> xt (bf16, D-innermost channels-last: [n][h*w][d][ci])
// ---------------------------------------------------------------------------
__global__ __launch_bounds__(256) void k_transpose(
    const float* __restrict__ x, unsigned short* __restrict__ xt)
{
    __shared__ unsigned lds[4][64 * 36];
    const int d = blockIdx.x, n = blockIdx.y, z = blockIdx.z;
    const int wave = threadIdx.x >> 6, lane = threadIdx.x & 63;
    const float* xb = x + (size_t)n * 64 * DHW + d * HW;
    unsigned short* xtb = xt + (size_t)n * DHW * 64;   // [hw][d][ci] inside
    unsigned* L = lds[wave];

    for (int c = z * 7 + wave; c < z * 7 + 7 && c < 49; c += 4) {
        const int P = c * 64;
#pragma unroll 4
        for (int cp = 0; cp < 32; ++cp) {
            const float a = xb[(size_t)(2 * cp) * DHW + P + lane];
            const float b = xb[(size_t)(2 * cp + 1) * DHW + P + lane];
            L[lane * 36 + cp] = cvt_pk_bf16(a, b);
        }
#pragma unroll
        for (int k = 0; k < 8; ++k) {
            const int r = (lane >> 3) + 8 * k;          // pixel within 64-chunk
            const uint4 v = *(const uint4*)&L[r * 36 + 4 * (lane & 7)];
            *(uint4*)((char*)xtb + ((size_t)(P + r) * 16 + d) * 128 + (lane & 7) * 16) = v;
        }
    }
}

// ---------------------------------------------------------------------------
// Weight prep -- lane-major packed fragments (one coalesced 1 KB wave read
// per fragment load):
//   BtO[tap][ks][lane]{short8}                 (16x16 frags, offset conv)
//   Bt1/Bt2[tap][cog][ksw][ksub][lane]{short8} (32x32x16 frags)
// 32x32 B mapping: co = cog*32 + (lane&31), ci = ksw*32 + ksub*16 +
// (lane>>5)*8 + e  -- mirror of the A-fragment (row=lane&31, k=(lane>>5)*8+e).
// ---------------------------------------------------------------------------
__global__ __launch_bounds__(256) void k_wprep(
    const float* __restrict__ w_off, const float* __restrict__ w1,
    const float* __restrict__ w2, unsigned short* __restrict__ BtO,
    unsigned short* __restrict__ Bt1, unsigned short* __restrict__ Bt2)
{
    const int i = blockIdx.x * 256 + threadIdx.x;
    if (i < 27648) {
        const int tap = i / 1024, r = i - tap * 1024;
        const int ks = r >> 9, r3 = r & 511, lane = r3 >> 3, e = r3 & 7;
        const int row = lane & 15;
        const int ci  = ks * 32 + (lane >> 4) * 8 + e;
        BtO[i] = (row < 8) ? (unsigned short)f2bf(w_off[(row * 64 + ci) * 27 + tap]) : 0;
    }
    if (i < 110592) {
        const int tap = i / 4096, r = i - tap * 4096;
        const int cog = r >> 11, r2 = r & 2047;
        const int ksw = r2 >> 10, r3 = r2 & 1023;
        const int ksub = r3 >> 9, r4 = r3 & 511;
        const int lane = r4 >> 3, e = r4 & 7;
        const int co = cog * 32 + (lane & 31);
        const int ci = ksw * 32 + ksub * 16 + (lane >> 5) * 8 + e;
        Bt1[i] = (unsigned short)f2bf(w1[(co * 64 + ci) * 27 + tap]);
        Bt2[i] = (unsigned short)f2bf(w2[(co * 64 + ci) * 27 + tap]);
    }
}

// ---------------------------------------------------------------------------
// Standard 3x3x3 conv via MFMA, LDS-staged. Block = (h, d, n), 512 thr.
// A-tile: 9 rows (3 dq x 3 hq) x 58 px x 64 ci bf16, row stride 72 shorts.
// Staging is ROW-STATIC (9 unrolled rows, px = tid>>3, no divides).
// NCO==8 : 16x16x32 path, 8 waves ks-split (unchanged, proven).
// NCO==64: 32x32x16 path -- wave (pxg, cog, ksw) = (M-half, N-half, ci-half).
//          Per tap: 2 A-reads + 2 B-loads + 2 MFMA (vs 4+2+4 with 16x16):
//          halves the LDS-read port occupancy that dominated the block
//          budget (~65% -> ~40%). ksw partials summed via E[2][64][65] LDS.
//          Epilogue fuses bucketed per-channel stats.
// ---------------------------------------------------------------------------
template<int NCO, bool BN, bool DIN>
__global__ __launch_bounds__(512) void k_conv(
    const unsigned short* __restrict__ src, const unsigned short* __restrict__ Bt,
    const float* __restrict__ bias, const float* __restrict__ scv,
    const float* __restrict__ shv, float* __restrict__ dst,
    float* __restrict__ osum, float* __restrict__ osq)
{
    __shared__ unsigned short A[538 * 72];   // 9*58=522 slots + 16 overrun pad
    int h, d, n, bucket;
    xcd_decode(h, d, n, bucket);
    const int tid = threadIdx.x;
    const int wave = tid >> 6, lane = tid & 63, lm = lane & 15, quad = lane >> 4;
    const int k8 = tid & 7;                  // fixed ci-chunk per thread

    float scr[8], shr[8];
    if constexpr (BN) {
#pragma unroll
        for (int e = 0; e < 8; ++e) { scr[e] = scv[k8 * 8 + e]; shr[e] = shv[k8 * 8 + e]; }
    }

    const unsigned short* snb = DIN ? (src + (size_t)n * DHW * 64)
                                    : (src + (size_t)(n * 16) * HW * 64);

    // ---- row-static staging: 9 rows x 464 tasks (58 px x 8 chunks) ----
    const int spx = tid >> 3;                // 0..63 (>=58 masked)
    const int wq  = spx - 1;
    const bool pxok = (tid < 464) & ((unsigned)wq < 56u);
#pragma unroll
    for (int row = 0; row < 9; ++row) {
        const int kd = row / 3, kh = row - (row / 3) * 3;
        const int dq = d + kd - 1, hq = h + kh - 1;
        uint4 pk = {0u, 0u, 0u, 0u};
        if (pxok & ((unsigned)dq < 16u) & ((unsigned)hq < 56u)) {
            const size_t off = DIN ? (((size_t)(hq * 56 + wq) * 16 + dq) * 64)
                                   : (((size_t)dq * HW + hq * 56 + wq) * 64);
            const ushort8 val = *(const ushort8*)(snb + off + k8 * 8);
            if constexpr (BN) {
                float f[8];
#pragma unroll
                for (int e = 0; e < 8; ++e)
                    f[e] = fmaxf(fmaf(bf2f(val[e]), scr[e], shr[e]), 0.f);
                pk.x = cvt_pk_bf16(f[0], f[1]);
                pk.y = cvt_pk_bf16(f[2], f[3]);
                pk.z = cvt_pk_bf16(f[4], f[5]);
                pk.w = cvt_pk_bf16(f[6], f[7]);
            } else {
                pk = *(const uint4*)&val;
            }
        }
        if (tid < 464) *(uint4*)&A[(size_t)(row * 58 + spx) * 72 + k8 * 8] = pk;
    }
    __syncthreads();

    if constexpr (NCO == 8) {
        // ---- ks-split: wave>>2 picks the ci half; wave&3 picks the m-frag ----
        const int ksw = wave >> 2, mf = wave & 3;
        f32x4 acc = (f32x4){0.f, 0.f, 0.f, 0.f};
        const unsigned short* Btb = Bt + ksw * 512;
        unsigned boff = (unsigned)lane * 8;
        short8 bc = *(const short8*)(Btb + boff);
        boff += 1024u;
        unsigned arow = (unsigned)(mf * 16 + lm) * 72 + quad * 8 + ksw * 32;
#pragma unroll 1
        for (int r9 = 0; r9 < 9; ++r9) {
#pragma unroll
            for (int kw = 0; kw < 3; ++kw) {
                const bool more = (kw < 2) | (r9 < 8);
                short8 bn;
                if (more) bn = *(const short8*)(Btb + boff);
                const short8 a = *(const short8*)&A[arow + kw * 72];
                acc = __builtin_amdgcn_mfma_f32_16x16x32_bf16(a, bc, acc, 0, 0, 0);
                if (more) { bc = bn; boff += 1024u; }
            }
            arow += 58 * 72;
        }
        __syncthreads();
        float* E = (float*)A;                // E[2][56*17]
#pragma unroll
        for (int r = 0; r < 4; ++r) {
            const int mm = mf * 16 + quad * 4 + r;
            if (mm < 56) E[ksw * 952 + mm * 17 + lm] = acc[r];
        }
        __syncthreads();
        if (lane < 56) {                     // co = wave, w0 = lane
            const float v = E[lane * 17 + wave] + E[952 + lane * 17 + wave] + bias[wave];
            dst[((size_t)(n * 8 + wave) * 16 + d) * HW + h * 56 + lane] = v;
        }
    } else {
        // ---- 32x32x16 K-loop ----
        const int pxg = wave & 1, cog = (wave >> 1) & 1, ksw = wave >> 2;
        f32x16 acc = (f32x16){0.f,0.f,0.f,0.f,0.f,0.f,0.f,0.f,
                              0.f,0.f,0.f,0.f,0.f,0.f,0.f,0.f};

        const unsigned short* Btb = Bt + (unsigned)(cog * 2 + ksw) * 1024;
        unsigned boff = (unsigned)lane * 8;
        short8 bc0 = *(const short8*)(Btb + boff);
        short8 bc1 = *(const short8*)(Btb + boff + 512);
        boff += 4096u;
        unsigned arow = (unsigned)(pxg * 32 + (lane & 31)) * 72 + ksw * 32 + (lane >> 5) * 8;

#pragma unroll 1
        for (int r9 = 0; r9 < 9; ++r9) {
#pragma unroll
            for (int kw = 0; kw < 3; ++kw) {
                const bool more = (kw < 2) | (r9 < 8);
                short8 bn0, bn1;
                if (more) {
                    bn0 = *(const short8*)(Btb + boff);
                    bn1 = *(const short8*)(Btb + boff + 512);
                }
                const unsigned ab = arow + kw * 72;
                const short8 a0 = *(const short8*)&A[ab];
                const short8 a1 = *(const short8*)&A[ab + 16];
                acc = __builtin_amdgcn_mfma_f32_32x32x16_bf16(a0, bc0, acc, 0, 0, 0);
                acc = __builtin_amdgcn_mfma_f32_32x32x16_bf16(a1, bc1, acc, 0, 0, 0);
                if (more) { bc0 = bn0; bc1 = bn1; boff += 4096u; }
            }
            arow += 58 * 72;
        }

        // ---- epilogue: ksw-partials -> E[2][64][65] -> fp32 NCDHW + stats ----
        __syncthreads();
        float* E = (float*)A;
#pragma unroll
        for (int reg = 0; reg < 16; ++reg) {
            const int pl = (reg & 3) + 8 * (reg >> 2) + 4 * (lane >> 5);
            E[ksw * 4160 + (pxg * 32 + pl) * 65 + cog * 32 + (lane & 31)] = acc[reg];
        }
        __syncthreads();
        const int co = tid >> 3, w8 = tid & 7;     // 8 lanes per channel
        const float bco = bias[co];
        float* drow = &dst[((size_t)(n * 64 + co) * 16 + d) * HW + h * 56];
        float s = 0.f, q = 0.f;
#pragma unroll
        for (int i = 0; i < 7; ++i) {
            const int w0 = w8 + 8 * i;
            const float v = E[w0 * 65 + co] + E[4160 + w0 * 65 + co] + bco;
            drow[w0] = v;
            s += v; q = fmaf(v, v, q);
        }
        s += __shfl_down(s, 1); q += __shfl_down(q, 1);
        s += __shfl_down(s, 2); q += __shfl_down(q, 2);
        s += __shfl_down(s, 4); q += __shfl_down(q, 4);
        if ((lane & 7) == 0) {
            atomicAdd(&osum[(bucket << 6) + co], s);
            atomicAdd(&osq [(bucket << 6) + co], q);
        }
    }
}

// ---------------------------------------------------------------------------
// Temporal deformable conv. 512 thr, 32x32x16 path (same decomposition as
// k_conv<64>). Staging BUILDS the interpolated field (g-minor dense gathers,
// masks folded into scalar lerp coefficients). Epilogue sums ksw-partials in
// f32, emits bf16 ch-last out1, and fuses bucketed per-channel stats (f32).
// ---------------------------------------------------------------------------
__global__ __launch_bounds__(512) void k_deform(
    const unsigned short* __restrict__ xt, const float* __restrict__ offo,
    const unsigned short* __restrict__ Bt, unsigned short* __restrict__ out1,
    float* __restrict__ osum, float* __restrict__ osq)
{
    __shared__ unsigned short A[538 * 72];
    int h, d, n, bucket;
    xcd_decode(h, d, n, bucket);
    const int tid = threadIdx.x;
    const int wave = tid >> 6, lane = tid & 63;

    // ---- prefetch the 3 offset values this thread needs (g-minor decode) ----
    float pv[3];
#pragma unroll
    for (int it = 0; it < 3; ++it) {
        const int c = tid + it * 512;
        float p = 0.f;
        if (c < 1392) {
            const int g = c & 7, pix = c >> 3;           // pix < 174
            const int hq3 = pix / 58, px = pix - hq3 * 58;
            const int habs = h + hq3 - 1, wq = px - 1;
            if (((unsigned)habs < 56u) & ((unsigned)wq < 56u))
                p = offo[((size_t)(n * 8 + g) * 16 + d) * HW + habs * 56 + wq] + (float)d;
        }
        pv[it] = p;
    }

    // ---- gather + lerp staging: 1392 tasks (174 px x 8 g), g-minor ----
#pragma unroll
    for (int it = 0; it < 3; ++it) {
        const int c = tid + it * 512;
        if (c >= 1392) break;
        const int g = c & 7, pix = c >> 3;
        const int hq3 = pix / 58, px = pix - hq3 * 58;
        const int habs = h + hq3 - 1, wq = px - 1;
        uint4 p0 = {0u,0u,0u,0u}, p1 = {0u,0u,0u,0u}, p2 = {0u,0u,0u,0u};
        if (((unsigned)habs < 56u) & ((unsigned)wq < 56u)) {
            const float p = pv[it];
            const float fl = floorf(p);
            const float fr = p - fl;
            const int i0 = (int)fl;
            const unsigned short* cb = xt + ((size_t)n * HW + habs * 56 + wq) * (16 * 64) + g * 8;
            float sv[4][8], m[4];
#pragma unroll
            for (int j = 0; j < 4; ++j) {
                const int dj = i0 - 1 + j;
                const bool ok = (unsigned)dj < 16u;
                m[j] = ok ? 1.f : 0.f;
                const ushort8 v = *(const ushort8*)(cb + (size_t)(ok ? dj : 0) * 64);
#pragma unroll
                for (int e = 0; e < 8; ++e) sv[j][e] = bf2f(v[e]);   // finite data; mask in coeffs
            }
            const float fi = 1.f - fr;
            const float w0a = fi * m[0], w0b = fr * m[1];
            const float w1a = fi * m[1], w1b = fr * m[2];
            const float w2a = fi * m[2], w2b = fr * m[3];
            float a0[8], a1[8], a2[8];
#pragma unroll
            for (int e = 0; e < 8; ++e) {
                a0[e] = fmaf(sv[1][e], w0b, sv[0][e] * w0a);
                a1[e] = fmaf(sv[2][e], w1b, sv[1][e] * w1a);
                a2[e] = fmaf(sv[3][e], w2b, sv[2][e] * w2a);
            }
            p0.x = cvt_pk_bf16(a0[0], a0[1]); p0.y = cvt_pk_bf16(a0[2], a0[3]);
            p0.z = cvt_pk_bf16(a0[4], a0[5]); p0.w = cvt_pk_bf16(a0[6], a0[7]);
            p1.x = cvt_pk_bf16(a1[0], a1[1]); p1.y = cvt_pk_bf16(a1[2], a1[3]);
            p1.z = cvt_pk_bf16(a1[4], a1[5]); p1.w = cvt_pk_bf16(a1[6], a1[7]);
            p2.x = cvt_pk_bf16(a2[0], a2[1]); p2.y = cvt_pk_bf16(a2[2], a2[3]);
            p2.z = cvt_pk_bf16(a2[4], a2[5]); p2.w = cvt_pk_bf16(a2[6], a2[7]);
        }
        const int sl = hq3 * 58 + px;
        *(uint4*)&A[(size_t)(sl          ) * 72 + g * 8] = p0;   // kd=0 rows 0..2
        *(uint4*)&A[(size_t)(sl + 3 * 58 ) * 72 + g * 8] = p1;   // kd=1 rows 3..5
        *(uint4*)&A[(size_t)(sl + 6 * 58 ) * 72 + g * 8] = p2;   // kd=2 rows 6..8
    }
    __syncthreads();

    // ---- 32x32x16 K-loop ----
    const int pxg = wave & 1, cog = (wave >> 1) & 1, ksw = wave >> 2;
    f32x16 acc = (f32x16){0.f,0.f,0.f,0.f,0.f,0.f,0.f,0.f,
                          0.f,0.f,0.f,0.f,0.f,0.f,0.f,0.f};

    const unsigned short* Btb = Bt + (unsigned)(cog * 2 + ksw) * 1024;
    unsigned boff = (unsigned)lane * 8;
    short8 bc0 = *(const short8*)(Btb + boff);
    short8 bc1 = *(const short8*)(Btb + boff + 512);
    boff += 4096u;
    unsigned arow = (unsigned)(pxg * 32 + (lane & 31)) * 72 + ksw * 32 + (lane >> 5) * 8;

#pragma unroll 1
    for (int r9 = 0; r9 < 9; ++r9) {
#pragma unroll
        for (int kw = 0; kw < 3; ++kw) {
            const bool more = (kw < 2) | (r9 < 8);
            short8 bn0, bn1;
            if (more) {
                bn0 = *(const short8*)(Btb + boff);
                bn1 = *(const short8*)(Btb + boff + 512);
            }
            const unsigned ab = arow + kw * 72;
            const short8 a0 = *(const short8*)&A[ab];
            const short8 a1 = *(const short8*)&A[ab + 16];
            acc = __builtin_amdgcn_mfma_f32_32x32x16_bf16(a0, bc0, acc, 0, 0, 0);
            acc = __builtin_amdgcn_mfma_f32_32x32x16_bf16(a1, bc1, acc, 0, 0, 0);
            if (more) { bc0 = bn0; bc1 = bn1; boff += 4096u; }
        }
        arow += 58 * 72;
    }

    // ---- epilogue: ksw-partials -> E[2][64][65] f32 -> bf16 out1 + stats ----
    __syncthreads();
    float* E = (float*)A;
#pragma unroll
    for (int reg = 0; reg < 16; ++reg) {
        const int pl = (reg & 3) + 8 * (reg >> 2) + 4 * (lane >> 5);
        E[ksw * 4160 + (pxg * 32 + pl) * 65 + cog * 32 + (lane & 31)] = acc[reg];
    }
    __syncthreads();
    const size_t pixb = ((size_t)(n * 16) + d) * HW + h * 56;
    if (tid < 448) {
        const int px = tid >> 3, kk = tid & 7;
        float v[8];
#pragma unroll
        for (int e = 0; e < 8; ++e)
            v[e] = E[px * 65 + kk * 8 + e] + E[4160 + px * 65 + kk * 8 + e];
        uint4 pk;
        pk.x = cvt_pk_bf16(v[0], v[1]); pk.y = cvt_pk_bf16(v[2], v[3]);
        pk.z = cvt_pk_bf16(v[4], v[5]); pk.w = cvt_pk_bf16(v[6], v[7]);
        *(uint4*)(out1 + (pixb + px) * 64 + kk * 8) = pk;
    }
    // per-channel stats (f32 partial sums; bucketed)
    const int co = tid >> 3, w8 = tid & 7;
    float s = 0.f, q = 0.f;
#pragma unroll
    for (int i = 0; i < 7; ++i) {
        const int w0 = w8 + 8 * i;
        const float v = E[w0 * 65 + co] + E[4160 + w0 * 65 + co];
        s += v; q = fmaf(v, v, q);
    }
    s += __shfl_down(s, 1); q += __shfl_down(q, 1);
    s += __shfl_down(s, 2); q += __shfl_down(q, 2);
    s += __shfl_down(s, 4); q += __shfl_down(q, 4);
    if ((lane & 7) == 0) {
        atomicAdd(&osum[(bucket << 6) + co], s);
        atomicAdd(&osq [(bucket << 6) + co], q);
    }
}

// ---------------- finalize BN from bucketed sums: scale/shift --------------
__global__ void k_finalize(const float* __restrict__ sums, const float* __restrict__ sqs,
                           const float* __restrict__ gamma, const float* __restrict__ beta,
                           float* __restrict__ scale, float* __restrict__ shift)
{
    const int c = threadIdx.x; // 64 threads
    float s = 0.f, q = 0.f;
#pragma unroll 8
    for (int b = 0; b < 64; ++b) {
        s += sums[(b << 6) + c];
        q += sqs [(b << 6) + c];
    }
    const float mean = s / CNT;
    const float var  = q / CNT - mean * mean;
    const float sc   = gamma[c] * rsqrtf(var + 1e-5f);
    scale[c] = sc;
    shift[c] = fmaf(-mean, sc, beta[c]);
}

// -------- BN2 + residual + ReLU: dst = relu(bn(raw) + x)  (float4) ---------
__global__ __launch_bounds__(256) void k_residual(
    float4* __restrict__ dst, const float4* __restrict__ raw,
    const float4* __restrict__ x,
    const float* __restrict__ scale, const float* __restrict__ shift)
{
    const int i = blockIdx.x * 256 + threadIdx.x;   // < 6422528
    const int c = (i / 12544) & 63;                  // wave-uniform
    const float sc = scale[c], sh = shift[c];
    float4 v = raw[i];
    const float4 xv = x[i];
    v.x = fmaxf(fmaf(v.x, sc, sh) + xv.x, 0.f);
    v.y = fmaxf(fmaf(v.y, sc, sh) + xv.y, 0.f);
    v.z = fmaxf(fmaf(v.z, sc, sh) + xv.z, 0.f);
    v.w = fmaxf(fmaf(v.w, sc, sh) + xv.w, 0.f);
    dst[i] = v;
}

extern "C" void kernel_launch(void* const* d_in, const int* in_sizes, int n_in,
                              void* d_out, int out_size, void* d_ws, size_t ws_size,
                              hipStream_t stream) {
    const float* x     = (const float*)d_in[0];
    const float* w_off = (const float*)d_in[1];
    const float* b_off = (const float*)d_in[2];
    const float* w1    = (const float*)d_in[3];
    const float* w2    = (const float*)d_in[4];
    const float* b2    = (const float*)d_in[5];
    const float* g1    = (const float*)d_in[6];
    const float* be1   = (const float*)d_in[7];
    const float* g2    = (const float*)d_in[8];
    const float* be2   = (const float*)d_in[9];

    // ---- buffer plan (proven round 10) ----
    // d_out: [0, 2*NEL) out1 | 52M weights | 53M bucketed stats (dead after
    //        finalizes, which complete before k_residual's overwrite) |
    //        [4*NEL,..) off_out | [0,4*NEL) final out (k_residual, LAST).
    // d_ws:  [0,2*NEL) xt -> overwritten by raw [0,4*NEL) | [4*NEL,+1K) sc/sh.
    float* out     = (float*)d_out;
    float* off_out = out + NEL;
    unsigned short* out1 = (unsigned short*)d_out;
    unsigned short* wb   = (unsigned short*)(out + 13000000);  // byte 52,000,000
    unsigned short* BtO  = wb;
    unsigned short* Bt1  = BtO + 27648;
    unsigned short* Bt2  = Bt1 + 110592;

    unsigned short* xt  = (unsigned short*)d_ws;
    float*          raw = (float*)d_ws;

    float* stb = (float*)((char*)d_out + 53000000);   // buckets ONLY
    float* dsum = stb,        * dsq = stb + 4096;
    float* csum = stb + 8192, * csq = stb + 12288;
    float* shp = (float*)d_ws + NEL;                  // proven 2 KiB region
    float* sc1 = shp,       * sh1 = shp + 64;
    float* sc2 = shp + 128, * sh2 = shp + 192;

    hipMemsetAsync(stb, 0, 16384 * sizeof(float), stream);

    k_transpose<<<dim3(16, 8, 7), 256, 0, stream>>>(x, xt);
    k_wprep<<<432, 256, 0, stream>>>(w_off, w1, w2, BtO, Bt1, Bt2);

    const dim3 cgrid(56, 16, 8);   // h, d, n (decoded via xcd_decode inside)
    k_conv<8, false, true><<<cgrid, 512, 0, stream>>>(xt, BtO, b_off, nullptr, nullptr, off_out, nullptr, nullptr);
    k_deform<<<cgrid, 512, 0, stream>>>(xt, off_out, Bt1, out1, dsum, dsq);

    k_finalize<<<1, 64, 0, stream>>>(dsum, dsq, g1, be1, sc1, sh1);

    k_conv<64, true, false><<<cgrid, 512, 0, stream>>>(out1, Bt2, b2, sc1, sh1, raw, csum, csq);

    k_finalize<<<1, 64, 0, stream>>>(csum, csq, g2, be2, sc2, sh2);
    k_residual<<<25088, 256, 0, stream>>>((float4*)out, (const float4*)raw, (const float4*)x, sc2, sh2);
}